// Round 11
// baseline (453.183 us; speedup 1.0000x reference)
//
#include <hip/hip_runtime.h>
#include <hip/hip_bf16.h>

// ---------------------------------------------------------------------------
// GraphSAGE (3x SAGEConv mean + linear head), CSR gather formulation.
// R11 = R10 + degree-sorted gather order:
//   nodes are permuted into 32 degree buckets (hist folded into scan_partial,
//   bin-scan into scan_final, scatter into fill_csr's launch) so each
//   aggregate wave's 4 nodes have near-equal degree -> no max-degree straggler.
// Established structure: prep merge, layer16 fused x-gather MFMA (K=32),
// split high-occupancy aggregate128 + lean MFMA GEMMs, head fused in layer 3.
// ---------------------------------------------------------------------------

#define SCAN_CHUNK 2048

typedef unsigned short bf16_t;
typedef unsigned int uint32;
typedef __attribute__((ext_vector_type(8))) short bf16x8;   // 8 bf16 = 4 VGPRs
typedef __attribute__((ext_vector_type(4))) float f32x4;

__device__ __forceinline__ bf16_t f2bf(float f) {
    uint32 u = __float_as_uint(f);
    u += 0x7fff + ((u >> 16) & 1);           // round-to-nearest-even
    return (bf16_t)(u >> 16);
}
__device__ __forceinline__ float bf2f(bf16_t b) {
    return __uint_as_float((uint32)b << 16);
}
__device__ __forceinline__ void acc8(float* acc, uint4 v) {
    acc[0] += bf2f((bf16_t)(v.x & 0xffff)); acc[1] += bf2f((bf16_t)(v.x >> 16));
    acc[2] += bf2f((bf16_t)(v.y & 0xffff)); acc[3] += bf2f((bf16_t)(v.y >> 16));
    acc[4] += bf2f((bf16_t)(v.z & 0xffff)); acc[5] += bf2f((bf16_t)(v.z >> 16));
    acc[6] += bf2f((bf16_t)(v.w & 0xffff)); acc[7] += bf2f((bf16_t)(v.w >> 16));
}

// ---- setup: zero deg + hist, convert three weight matrices to bf16 --------
__global__ __launch_bounds__(256) void prep_kernel(
    int* __restrict__ deg, int* __restrict__ hist, int N,
    const float* __restrict__ Wl1, const float* __restrict__ Wr1, bf16_t* __restrict__ w1,
    const float* __restrict__ Wl2, const float* __restrict__ Wr2, bf16_t* __restrict__ w2,
    const float* __restrict__ Wl3, const float* __restrict__ Wr3, bf16_t* __restrict__ w3) {
    const int nZero = (N + 255) >> 8;
    const int b = blockIdx.x;
    const int t = threadIdx.x;
    if (b < nZero) {
        int i = b * 256 + t;
        if (i < N) deg[i] = 0;
    } else if (b < nZero + 16) {
        int idx = (b - nZero) * 256 + t;         // 0..4095
        int o = idx >> 5, k = idx & 31;
        float v = (k < 16) ? Wl1[o * 16 + k] : Wr1[o * 16 + k - 16];
        w1[idx] = f2bf(v);
    } else if (b < nZero + 144) {
        int idx = (b - nZero - 16) * 256 + t;    // 0..32767
        int o = idx >> 8, k = idx & 255;
        float v = (k < 128) ? Wl2[o * 128 + k] : Wr2[o * 128 + k - 128];
        w2[idx] = f2bf(v);
    } else if (b < nZero + 272) {
        int idx = (b - nZero - 144) * 256 + t;
        int o = idx >> 8, k = idx & 255;
        float v = (k < 128) ? Wl3[o * 128 + k] : Wr3[o * 128 + k - 128];
        w3[idx] = f2bf(v);
    } else {
        if (t < 32) hist[t] = 0;
    }
}

__global__ void count_deg_kernel(const int* __restrict__ dst, int* __restrict__ deg, int E) {
    int e = blockIdx.x * 256 + threadIdx.x;
    if (e < E) atomicAdd(&deg[dst[e]], 1);
}

// per-block sums of deg + 32-bin degree histogram (folded in: same pass)
__global__ __launch_bounds__(256) void scan_partial_kernel(
    const int* __restrict__ deg, int* __restrict__ blocksum,
    int* __restrict__ hist, int N) {
    __shared__ int s[256];
    __shared__ int lh[32];
    const int t = threadIdx.x;
    if (t < 32) lh[t] = 0;
    __syncthreads();
    const int base = blockIdx.x * SCAN_CHUNK + t * 8;
    int sum = 0;
    #pragma unroll
    for (int j = 0; j < 8; ++j) {
        int i = base + j;
        if (i < N) {
            int d = deg[i];
            sum += d;
            atomicAdd(&lh[min(d, 31)], 1);
        }
    }
    s[t] = sum;
    __syncthreads();
    #pragma unroll
    for (int off = 128; off > 0; off >>= 1) {
        if (t < off) s[t] += s[t + off];
        __syncthreads();
    }
    if (t == 0) blocksum[blockIdx.x] = s[0];
    if (t < 32 && lh[t]) atomicAdd(&hist[t], lh[t]);
}

// rowptr/cursor/inv + 32-bin exclusive scan -> bincur (block 0)
__global__ __launch_bounds__(256) void scan_final_kernel(
    const int* __restrict__ deg, const int* __restrict__ blocksum,
    const int* __restrict__ hist, int* __restrict__ bincur,
    int* __restrict__ rowptr, int* __restrict__ cursor,
    float* __restrict__ inv, int N) {
    __shared__ int s[256];
    __shared__ int blockoff_s;
    const int t = threadIdx.x;
    if (blockIdx.x == 0 && t == 0) {
        int run2 = 0;
        for (int b2 = 0; b2 < 32; ++b2) { bincur[b2] = run2; run2 += hist[b2]; }
    }
    if (t == 0) {
        int off = 0;
        for (int b = 0; b < (int)blockIdx.x; ++b) off += blocksum[b];
        blockoff_s = off;
    }
    const int base = blockIdx.x * SCAN_CHUNK + t * 8;
    int v[8];
    int sum = 0;
    #pragma unroll
    for (int j = 0; j < 8; ++j) {
        int i = base + j;
        v[j] = (i < N) ? deg[i] : 0;
        sum += v[j];
    }
    s[t] = sum;
    __syncthreads();
    for (int off = 1; off < 256; off <<= 1) {
        int val = (t >= off) ? s[t - off] : 0;
        __syncthreads();
        s[t] += val;
        __syncthreads();
    }
    int run = blockoff_s + ((t == 0) ? 0 : s[t - 1]);
    #pragma unroll
    for (int j = 0; j < 8; ++j) {
        int i = base + j;
        if (i < N) {
            rowptr[i] = run;
            cursor[i] = run;
            inv[i] = 1.0f / (float)max(v[j], 1);
            run += v[j];
        }
    }
    if ((int)blockIdx.x == (int)gridDim.x - 1 && t == 255) rowptr[N] = run;
}

// CSR col fill (edge blocks) + degree-bucket permutation scatter (node blocks)
__global__ void fill_scatter_kernel(
    const int* __restrict__ src, const int* __restrict__ dst,
    int* __restrict__ cursor, int* __restrict__ col, int E,
    const int* __restrict__ deg, int* __restrict__ bincur,
    int* __restrict__ perm, int N, int nEdgeBlocks) {
    const int b = blockIdx.x;
    const int t = threadIdx.x;
    if (b < nEdgeBlocks) {
        int e = b * 256 + t;
        if (e >= E) return;
        int pos = atomicAdd(&cursor[dst[e]], 1);
        col[pos] = src[e];
    } else {
        int i = (b - nEdgeBlocks) * 256 + t;
        if (i >= N) return;
        int bin = min(deg[i], 31);
        int pos = atomicAdd(&bincur[bin], 1);
        perm[pos] = i;
    }
}

// ---- layer 1 fused: gather x-mean + MFMA (K=32) --------------------------
__global__ __launch_bounds__(256) void layer16_fused_kernel(
    const float* __restrict__ x, const int* __restrict__ rowptr,
    const int* __restrict__ col, const float* __restrict__ inv,
    const bf16_t* __restrict__ wbf1, const float* __restrict__ bias,
    bf16_t* __restrict__ hout, int n) {
    const int t = threadIdx.x;
    const int lane = t & 63;
    const int wave = t >> 6;
    const int r = lane & 15;
    const int q = lane >> 4;
    const int m0 = blockIdx.x * 64 + (wave >> 1) * 32;
    const int nb = (wave & 1) * 64;

    bf16x8 aF[2];
    #pragma unroll
    for (int mt = 0; mt < 2; ++mt) {
        int node = m0 + mt * 16 + r;
        if (node >= n) node = n - 1;
        float acc[8];
        if (q < 2) {
            #pragma unroll
            for (int j = 0; j < 8; ++j) acc[j] = 0.f;
            const int lo = rowptr[node], hi = rowptr[node + 1];
            int e = lo;
            for (; e + 1 < hi; e += 2) {
                int s0 = col[e], s1 = col[e + 1];
                float4 u0 = *(const float4*)&x[s0 * 16 + q * 8];
                float4 u1 = *(const float4*)&x[s0 * 16 + q * 8 + 4];
                float4 u2 = *(const float4*)&x[s1 * 16 + q * 8];
                float4 u3 = *(const float4*)&x[s1 * 16 + q * 8 + 4];
                acc[0] += u0.x + u2.x; acc[1] += u0.y + u2.y;
                acc[2] += u0.z + u2.z; acc[3] += u0.w + u2.w;
                acc[4] += u1.x + u3.x; acc[5] += u1.y + u3.y;
                acc[6] += u1.z + u3.z; acc[7] += u1.w + u3.w;
            }
            if (e < hi) {
                int s0 = col[e];
                float4 u0 = *(const float4*)&x[s0 * 16 + q * 8];
                float4 u1 = *(const float4*)&x[s0 * 16 + q * 8 + 4];
                acc[0] += u0.x; acc[1] += u0.y; acc[2] += u0.z; acc[3] += u0.w;
                acc[4] += u1.x; acc[5] += u1.y; acc[6] += u1.z; acc[7] += u1.w;
            }
            float iv = inv[node];
            #pragma unroll
            for (int j = 0; j < 8; ++j) acc[j] *= iv;
        } else {
            float4 u0 = *(const float4*)&x[node * 16 + (q - 2) * 8];
            float4 u1 = *(const float4*)&x[node * 16 + (q - 2) * 8 + 4];
            acc[0] = u0.x; acc[1] = u0.y; acc[2] = u0.z; acc[3] = u0.w;
            acc[4] = u1.x; acc[5] = u1.y; acc[6] = u1.z; acc[7] = u1.w;
        }
        #pragma unroll
        for (int j = 0; j < 8; ++j) aF[mt][j] = (short)f2bf(acc[j]);
    }

    #pragma unroll
    for (int nt = 0; nt < 4; ++nt) {
        const int cidx = nb + nt * 16 + r;
        bf16x8 bF = *(const bf16x8*)(wbf1 + (size_t)cidx * 32 + q * 8);
        f32x4 acc0 = {0.f, 0.f, 0.f, 0.f};
        f32x4 acc1 = {0.f, 0.f, 0.f, 0.f};
        acc0 = __builtin_amdgcn_mfma_f32_16x16x32_bf16(aF[0], bF, acc0, 0, 0, 0);
        acc1 = __builtin_amdgcn_mfma_f32_16x16x32_bf16(aF[1], bF, acc1, 0, 0, 0);
        float bo = bias[cidx];
        #pragma unroll
        for (int reg = 0; reg < 4; ++reg) {
            int row0 = m0 + q * 4 + reg;
            if (row0 < n)
                hout[(size_t)row0 * 128 + cidx] = f2bf(fmaxf(acc0[reg] + bo, 0.0f));
            int row1 = m0 + 16 + q * 4 + reg;
            if (row1 < n)
                hout[(size_t)row1 * 128 + cidx] = f2bf(fmaxf(acc1[reg] + bo, 0.0f));
        }
    }
}

// ---- degree-sorted coalesced mean aggregate: 16 lanes/node, 16B/lane,
// unroll-4; nodes taken in bucket-permuted order so a wave's 4 nodes have
// near-equal degree (no max-degree straggler).
__global__ __launch_bounds__(256) void aggregate128_kernel(
    const bf16_t* __restrict__ h, const int* __restrict__ rowptr,
    const int* __restrict__ col, const float* __restrict__ inv,
    const int* __restrict__ perm, bf16_t* __restrict__ aggb, int N) {
    const int t = threadIdx.x;
    const int gid = blockIdx.x * 16 + (t >> 4);
    const int li = t & 15;
    if (gid >= N) return;
    const int node = perm[gid];
    const int lo = rowptr[node], hi = rowptr[node + 1];
    float acc[8];
    #pragma unroll
    for (int j = 0; j < 8; ++j) acc[j] = 0.0f;
    int e = lo;
    for (; e + 3 < hi; e += 4) {
        int s0 = col[e], s1 = col[e + 1], s2 = col[e + 2], s3 = col[e + 3];
        uint4 v0 = *(const uint4*)&h[(size_t)s0 * 128 + li * 8];
        uint4 v1 = *(const uint4*)&h[(size_t)s1 * 128 + li * 8];
        uint4 v2 = *(const uint4*)&h[(size_t)s2 * 128 + li * 8];
        uint4 v3 = *(const uint4*)&h[(size_t)s3 * 128 + li * 8];
        acc8(acc, v0);
        acc8(acc, v1);
        acc8(acc, v2);
        acc8(acc, v3);
    }
    for (; e < hi; ++e) {
        uint4 v0 = *(const uint4*)&h[(size_t)col[e] * 128 + li * 8];
        acc8(acc, v0);
    }
    const float iv = inv[node];
    uint4 pk;
    pk.x = (uint32)f2bf(acc[0] * iv) | ((uint32)f2bf(acc[1] * iv) << 16);
    pk.y = (uint32)f2bf(acc[2] * iv) | ((uint32)f2bf(acc[3] * iv) << 16);
    pk.z = (uint32)f2bf(acc[4] * iv) | ((uint32)f2bf(acc[5] * iv) << 16);
    pk.w = (uint32)f2bf(acc[6] * iv) | ((uint32)f2bf(acc[7] * iv) << 16);
    *(uint4*)&aggb[(size_t)node * 128 + li * 8] = pk;
}

// ---- layer 2: MFMA bf16 GEMM, K=256, fragments straight from global ------
__global__ __launch_bounds__(256) void layer128_mfma_kernel(
    const bf16_t* __restrict__ aggb, const bf16_t* __restrict__ hin,
    const bf16_t* __restrict__ wbf, const float* __restrict__ bias,
    bf16_t* __restrict__ hout, int n) {
    const int t = threadIdx.x;
    const int lane = t & 63;
    const int wave = t >> 6;
    const int r = lane & 15;
    const int q = lane >> 4;
    const int m0 = blockIdx.x * 64 + (wave >> 1) * 32;
    const int nb = (wave & 1) * 64;

    bf16x8 aF[2][8];
    #pragma unroll
    for (int mt = 0; mt < 2; ++mt) {
        int node = m0 + mt * 16 + r;
        if (node >= n) node = n - 1;
        const bf16_t* arow = aggb + (size_t)node * 128;
        const bf16_t* hrow = hin + (size_t)node * 128;
        #pragma unroll
        for (int ks = 0; ks < 4; ++ks)
            aF[mt][ks] = *(const bf16x8*)(arow + ks * 32 + q * 8);
        #pragma unroll
        for (int ks = 0; ks < 4; ++ks)
            aF[mt][4 + ks] = *(const bf16x8*)(hrow + ks * 32 + q * 8);
    }

    #pragma unroll
    for (int nt = 0; nt < 4; ++nt) {
        const int cidx = nb + nt * 16 + r;
        const bf16_t* wrow = wbf + (size_t)cidx * 256;
        f32x4 acc0 = {0.f, 0.f, 0.f, 0.f};
        f32x4 acc1 = {0.f, 0.f, 0.f, 0.f};
        #pragma unroll
        for (int ks = 0; ks < 8; ++ks) {
            bf16x8 bF = *(const bf16x8*)(wrow + ks * 32 + q * 8);
            acc0 = __builtin_amdgcn_mfma_f32_16x16x32_bf16(aF[0][ks], bF, acc0, 0, 0, 0);
            acc1 = __builtin_amdgcn_mfma_f32_16x16x32_bf16(aF[1][ks], bF, acc1, 0, 0, 0);
        }
        float bo = bias[cidx];
        #pragma unroll
        for (int reg = 0; reg < 4; ++reg) {
            int row0 = m0 + q * 4 + reg;
            if (row0 < n)
                hout[(size_t)row0 * 128 + cidx] = f2bf(fmaxf(acc0[reg] + bo, 0.0f));
            int row1 = m0 + 16 + q * 4 + reg;
            if (row1 < n)
                hout[(size_t)row1 * 128 + cidx] = f2bf(fmaxf(acc1[reg] + bo, 0.0f));
        }
    }
}

// ---- layer 3 + head fused via LDS tile -----------------------------------
__global__ __launch_bounds__(256) void layer128_head_mfma_kernel(
    const bf16_t* __restrict__ aggb, const bf16_t* __restrict__ hin,
    const bf16_t* __restrict__ wbf, const float* __restrict__ bias,
    const float* __restrict__ Wh, const float* __restrict__ bh,
    float* __restrict__ out, int n) {
    __shared__ bf16_t hs[64][132];

    const int t = threadIdx.x;
    const int lane = t & 63;
    const int wave = t >> 6;
    const int r = lane & 15;
    const int q = lane >> 4;
    const int n0 = blockIdx.x * 64;
    const int m0 = n0 + (wave >> 1) * 32;
    const int nb = (wave & 1) * 64;

    bf16x8 aF[2][8];
    #pragma unroll
    for (int mt = 0; mt < 2; ++mt) {
        int node = m0 + mt * 16 + r;
        if (node >= n) node = n - 1;
        const bf16_t* arow = aggb + (size_t)node * 128;
        const bf16_t* hrow = hin + (size_t)node * 128;
        #pragma unroll
        for (int ks = 0; ks < 4; ++ks)
            aF[mt][ks] = *(const bf16x8*)(arow + ks * 32 + q * 8);
        #pragma unroll
        for (int ks = 0; ks < 4; ++ks)
            aF[mt][4 + ks] = *(const bf16x8*)(hrow + ks * 32 + q * 8);
    }

    const int mloc = (wave >> 1) * 32;
    #pragma unroll
    for (int nt = 0; nt < 4; ++nt) {
        const int cidx = nb + nt * 16 + r;
        const bf16_t* wrow = wbf + (size_t)cidx * 256;
        f32x4 acc0 = {0.f, 0.f, 0.f, 0.f};
        f32x4 acc1 = {0.f, 0.f, 0.f, 0.f};
        #pragma unroll
        for (int ks = 0; ks < 8; ++ks) {
            bf16x8 bF = *(const bf16x8*)(wrow + ks * 32 + q * 8);
            acc0 = __builtin_amdgcn_mfma_f32_16x16x32_bf16(aF[0][ks], bF, acc0, 0, 0, 0);
            acc1 = __builtin_amdgcn_mfma_f32_16x16x32_bf16(aF[1][ks], bF, acc1, 0, 0, 0);
        }
        float bo = bias[cidx];
        #pragma unroll
        for (int reg = 0; reg < 4; ++reg) {
            hs[mloc + q * 4 + reg][cidx]      = f2bf(fmaxf(acc0[reg] + bo, 0.0f));
            hs[mloc + 16 + q * 4 + reg][cidx] = f2bf(fmaxf(acc1[reg] + bo, 0.0f));
        }
    }
    __syncthreads();

    const int nl = t >> 2;
    const int o  = t & 3;
    const int node = n0 + nl;
    if (node >= n) return;
    const float* wr = Wh + o * 128;
    float acc = bh[o];
    #pragma unroll
    for (int kb = 0; kb < 16; ++kb) {
        bf16x8 hv = *(const bf16x8*)&hs[nl][kb * 8];
        float4 w0 = *(const float4*)&wr[kb * 8];
        float4 w1 = *(const float4*)&wr[kb * 8 + 4];
        acc = fmaf(bf2f((bf16_t)hv[0]), w0.x, acc);
        acc = fmaf(bf2f((bf16_t)hv[1]), w0.y, acc);
        acc = fmaf(bf2f((bf16_t)hv[2]), w0.z, acc);
        acc = fmaf(bf2f((bf16_t)hv[3]), w0.w, acc);
        acc = fmaf(bf2f((bf16_t)hv[4]), w1.x, acc);
        acc = fmaf(bf2f((bf16_t)hv[5]), w1.y, acc);
        acc = fmaf(bf2f((bf16_t)hv[6]), w1.z, acc);
        acc = fmaf(bf2f((bf16_t)hv[7]), w1.w, acc);
    }
    out[(size_t)node * 4 + o] = acc;
}

extern "C" void kernel_launch(void* const* d_in, const int* in_sizes, int n_in,
                              void* d_out, int out_size, void* d_ws, size_t ws_size,
                              hipStream_t stream) {
    const float* x   = (const float*)d_in[0];
    const int*   ei  = (const int*)d_in[1];
    const float* Wl1 = (const float*)d_in[2];
    const float* Wr1 = (const float*)d_in[3];
    const float* b1  = (const float*)d_in[4];
    const float* Wl2 = (const float*)d_in[5];
    const float* Wr2 = (const float*)d_in[6];
    const float* b2  = (const float*)d_in[7];
    const float* Wl3 = (const float*)d_in[8];
    const float* Wr3 = (const float*)d_in[9];
    const float* b3  = (const float*)d_in[10];
    const float* Wh  = (const float*)d_in[11];
    const float* bh  = (const float*)d_in[12];
    float* out = (float*)d_out;

    const int N = in_sizes[0] / 16;
    const int E = in_sizes[1] / 2;
    const int* src = ei;
    const int* dst = ei + E;

    const int nScanBlocks = (N + SCAN_CHUNK - 1) / SCAN_CHUNK;
    const int nZero = (N + 255) >> 8;

    int* deg       = (int*)d_ws;                       // N
    int* rowptr    = deg + N;                          // N+1 (pad 8)
    int* cursor    = rowptr + (N + 8);                 // N
    int* blocksum  = cursor + N;                       // pad 64
    int* hist      = blocksum + 64;                    // 32 (pad 32)
    int* bincur    = hist + 32;                        // 32
    int* perm      = bincur + 32;                      // N
    int* col       = perm + N;                         // E
    float* inv     = (float*)(col + E);                // N
    bf16_t* aggb   = (bf16_t*)(inv + N);               // N*128 bf16
    bf16_t* hA     = aggb + (size_t)N * 128;           // N*128 bf16
    bf16_t* hB     = hA + (size_t)N * 128;             // N*128 bf16
    bf16_t* wbf1   = hB + (size_t)N * 128;             // 128*32 bf16
    bf16_t* wbf2   = wbf1 + 128 * 32;                  // 128*256 bf16
    bf16_t* wbf3   = wbf2 + 128 * 256;                 // 128*256 bf16

    const int B = 256;
    auto blocks = [](long total, int b) { return (int)((total + b - 1) / b); };
    const int nEdgeBlocks = blocks(E, B);
    const int nNodeBlocks = blocks(N, B);

    // ---- setup + CSR build + degree-bucket perm (5 dispatches) ----
    prep_kernel<<<nZero + 273, B, 0, stream>>>(deg, hist, N, Wl1, Wr1, wbf1,
                                               Wl2, Wr2, wbf2, Wl3, Wr3, wbf3);
    count_deg_kernel<<<nEdgeBlocks, B, 0, stream>>>(dst, deg, E);
    scan_partial_kernel<<<nScanBlocks, B, 0, stream>>>(deg, blocksum, hist, N);
    scan_final_kernel<<<nScanBlocks, B, 0, stream>>>(deg, blocksum, hist, bincur,
                                                     rowptr, cursor, inv, N);
    fill_scatter_kernel<<<nEdgeBlocks + nNodeBlocks, B, 0, stream>>>(
        src, dst, cursor, col, E, deg, bincur, perm, N, nEdgeBlocks);

    // ---- layer 1: fused x-gather + MFMA (K=32) ----
    layer16_fused_kernel<<<blocks(N, 64), B, 0, stream>>>(
        x, rowptr, col, inv, wbf1, b1, hA, N);

    // ---- layer 2: degree-sorted aggregate + MFMA GEMM ----
    aggregate128_kernel<<<blocks(N, 16), B, 0, stream>>>(hA, rowptr, col, inv, perm, aggb, N);
    layer128_mfma_kernel<<<blocks(N, 64), B, 0, stream>>>(aggb, hA, wbf2, b2, hB, N);

    // ---- layer 3 + head fused ----
    aggregate128_kernel<<<blocks(N, 16), B, 0, stream>>>(hB, rowptr, col, inv, perm, aggb, N);
    layer128_head_mfma_kernel<<<blocks(N, 64), B, 0, stream>>>(
        aggb, hB, wbf3, b3, Wh, bh, out, N);
}

// Round 12
// 300.811 us; speedup vs baseline: 1.5065x; 1.5065x over previous
//
#include <hip/hip_runtime.h>
#include <hip/hip_bf16.h>

// ---------------------------------------------------------------------------
// GraphSAGE (3x SAGEConv mean + linear head), CSR gather formulation.
// R12 = R10 (best: 295us) + aggregate unroll-8.
// R11 lesson: degree-bucket permutation cost 158us of atomic contention
// (50K atomicAdds on 32 counters) and its benefit measured ~0 — the
// aggregates are latency/BW-saturated, not divergence-limited. Reverted.
// Established structure: prep merge (zero deg + 3 W converts), layer16
// fused x-gather MFMA (K=32), split high-occupancy coalesced aggregate128
// + lean no-LDS MFMA GEMMs (K=256), head fused into layer 3 epilogue.
// ---------------------------------------------------------------------------

#define SCAN_CHUNK 2048

typedef unsigned short bf16_t;
typedef unsigned int uint32;
typedef __attribute__((ext_vector_type(8))) short bf16x8;   // 8 bf16 = 4 VGPRs
typedef __attribute__((ext_vector_type(4))) float f32x4;

__device__ __forceinline__ bf16_t f2bf(float f) {
    uint32 u = __float_as_uint(f);
    u += 0x7fff + ((u >> 16) & 1);           // round-to-nearest-even
    return (bf16_t)(u >> 16);
}
__device__ __forceinline__ float bf2f(bf16_t b) {
    return __uint_as_float((uint32)b << 16);
}
__device__ __forceinline__ void acc8(float* acc, uint4 v) {
    acc[0] += bf2f((bf16_t)(v.x & 0xffff)); acc[1] += bf2f((bf16_t)(v.x >> 16));
    acc[2] += bf2f((bf16_t)(v.y & 0xffff)); acc[3] += bf2f((bf16_t)(v.y >> 16));
    acc[4] += bf2f((bf16_t)(v.z & 0xffff)); acc[5] += bf2f((bf16_t)(v.z >> 16));
    acc[6] += bf2f((bf16_t)(v.w & 0xffff)); acc[7] += bf2f((bf16_t)(v.w >> 16));
}

// ---- setup: zero deg + convert all three weight matrices to bf16 ----------
__global__ __launch_bounds__(256) void prep_kernel(
    int* __restrict__ deg, int N,
    const float* __restrict__ Wl1, const float* __restrict__ Wr1, bf16_t* __restrict__ w1,
    const float* __restrict__ Wl2, const float* __restrict__ Wr2, bf16_t* __restrict__ w2,
    const float* __restrict__ Wl3, const float* __restrict__ Wr3, bf16_t* __restrict__ w3) {
    const int nZero = (N + 255) >> 8;
    const int b = blockIdx.x;
    const int t = threadIdx.x;
    if (b < nZero) {
        int i = b * 256 + t;
        if (i < N) deg[i] = 0;
    } else if (b < nZero + 16) {
        int idx = (b - nZero) * 256 + t;         // 0..4095
        int o = idx >> 5, k = idx & 31;
        float v = (k < 16) ? Wl1[o * 16 + k] : Wr1[o * 16 + k - 16];
        w1[idx] = f2bf(v);
    } else if (b < nZero + 144) {
        int idx = (b - nZero - 16) * 256 + t;    // 0..32767
        int o = idx >> 8, k = idx & 255;
        float v = (k < 128) ? Wl2[o * 128 + k] : Wr2[o * 128 + k - 128];
        w2[idx] = f2bf(v);
    } else {
        int idx = (b - nZero - 144) * 256 + t;
        int o = idx >> 8, k = idx & 255;
        float v = (k < 128) ? Wl3[o * 128 + k] : Wr3[o * 128 + k - 128];
        w3[idx] = f2bf(v);
    }
}

__global__ void count_deg_kernel(const int* __restrict__ dst, int* __restrict__ deg, int E) {
    int e = blockIdx.x * 256 + threadIdx.x;
    if (e < E) atomicAdd(&deg[dst[e]], 1);
}

__global__ __launch_bounds__(256) void scan_partial_kernel(
    const int* __restrict__ deg, int* __restrict__ blocksum, int N) {
    __shared__ int s[256];
    const int t = threadIdx.x;
    const int base = blockIdx.x * SCAN_CHUNK + t * 8;
    int sum = 0;
    #pragma unroll
    for (int j = 0; j < 8; ++j) {
        int i = base + j;
        if (i < N) sum += deg[i];
    }
    s[t] = sum;
    __syncthreads();
    #pragma unroll
    for (int off = 128; off > 0; off >>= 1) {
        if (t < off) s[t] += s[t + off];
        __syncthreads();
    }
    if (t == 0) blocksum[blockIdx.x] = s[0];
}

__global__ __launch_bounds__(256) void scan_final_kernel(
    const int* __restrict__ deg, const int* __restrict__ blocksum,
    int* __restrict__ rowptr, int* __restrict__ cursor,
    float* __restrict__ inv, int N) {
    __shared__ int s[256];
    __shared__ int blockoff_s;
    const int t = threadIdx.x;
    if (t == 0) {
        int off = 0;
        for (int b = 0; b < (int)blockIdx.x; ++b) off += blocksum[b];
        blockoff_s = off;
    }
    const int base = blockIdx.x * SCAN_CHUNK + t * 8;
    int v[8];
    int sum = 0;
    #pragma unroll
    for (int j = 0; j < 8; ++j) {
        int i = base + j;
        v[j] = (i < N) ? deg[i] : 0;
        sum += v[j];
    }
    s[t] = sum;
    __syncthreads();
    for (int off = 1; off < 256; off <<= 1) {
        int val = (t >= off) ? s[t - off] : 0;
        __syncthreads();
        s[t] += val;
        __syncthreads();
    }
    int run = blockoff_s + ((t == 0) ? 0 : s[t - 1]);
    #pragma unroll
    for (int j = 0; j < 8; ++j) {
        int i = base + j;
        if (i < N) {
            rowptr[i] = run;
            cursor[i] = run;
            inv[i] = 1.0f / (float)max(v[j], 1);
            run += v[j];
        }
    }
    if ((int)blockIdx.x == (int)gridDim.x - 1 && t == 255) rowptr[N] = run;
}

__global__ void fill_csr_kernel(const int* __restrict__ src, const int* __restrict__ dst,
                                int* __restrict__ cursor, int* __restrict__ col, int E) {
    int e = blockIdx.x * 256 + threadIdx.x;
    if (e >= E) return;
    int pos = atomicAdd(&cursor[dst[e]], 1);
    col[pos] = src[e];
}

// ---- layer 1 fused: gather x-mean + MFMA (K=32) --------------------------
__global__ __launch_bounds__(256) void layer16_fused_kernel(
    const float* __restrict__ x, const int* __restrict__ rowptr,
    const int* __restrict__ col, const float* __restrict__ inv,
    const bf16_t* __restrict__ wbf1, const float* __restrict__ bias,
    bf16_t* __restrict__ hout, int n) {
    const int t = threadIdx.x;
    const int lane = t & 63;
    const int wave = t >> 6;
    const int r = lane & 15;
    const int q = lane >> 4;
    const int m0 = blockIdx.x * 64 + (wave >> 1) * 32;
    const int nb = (wave & 1) * 64;

    bf16x8 aF[2];
    #pragma unroll
    for (int mt = 0; mt < 2; ++mt) {
        int node = m0 + mt * 16 + r;
        if (node >= n) node = n - 1;
        float acc[8];
        if (q < 2) {
            #pragma unroll
            for (int j = 0; j < 8; ++j) acc[j] = 0.f;
            const int lo = rowptr[node], hi = rowptr[node + 1];
            int e = lo;
            for (; e + 1 < hi; e += 2) {
                int s0 = col[e], s1 = col[e + 1];
                float4 u0 = *(const float4*)&x[s0 * 16 + q * 8];
                float4 u1 = *(const float4*)&x[s0 * 16 + q * 8 + 4];
                float4 u2 = *(const float4*)&x[s1 * 16 + q * 8];
                float4 u3 = *(const float4*)&x[s1 * 16 + q * 8 + 4];
                acc[0] += u0.x + u2.x; acc[1] += u0.y + u2.y;
                acc[2] += u0.z + u2.z; acc[3] += u0.w + u2.w;
                acc[4] += u1.x + u3.x; acc[5] += u1.y + u3.y;
                acc[6] += u1.z + u3.z; acc[7] += u1.w + u3.w;
            }
            if (e < hi) {
                int s0 = col[e];
                float4 u0 = *(const float4*)&x[s0 * 16 + q * 8];
                float4 u1 = *(const float4*)&x[s0 * 16 + q * 8 + 4];
                acc[0] += u0.x; acc[1] += u0.y; acc[2] += u0.z; acc[3] += u0.w;
                acc[4] += u1.x; acc[5] += u1.y; acc[6] += u1.z; acc[7] += u1.w;
            }
            float iv = inv[node];
            #pragma unroll
            for (int j = 0; j < 8; ++j) acc[j] *= iv;
        } else {
            float4 u0 = *(const float4*)&x[node * 16 + (q - 2) * 8];
            float4 u1 = *(const float4*)&x[node * 16 + (q - 2) * 8 + 4];
            acc[0] = u0.x; acc[1] = u0.y; acc[2] = u0.z; acc[3] = u0.w;
            acc[4] = u1.x; acc[5] = u1.y; acc[6] = u1.z; acc[7] = u1.w;
        }
        #pragma unroll
        for (int j = 0; j < 8; ++j) aF[mt][j] = (short)f2bf(acc[j]);
    }

    #pragma unroll
    for (int nt = 0; nt < 4; ++nt) {
        const int cidx = nb + nt * 16 + r;
        bf16x8 bF = *(const bf16x8*)(wbf1 + (size_t)cidx * 32 + q * 8);
        f32x4 acc0 = {0.f, 0.f, 0.f, 0.f};
        f32x4 acc1 = {0.f, 0.f, 0.f, 0.f};
        acc0 = __builtin_amdgcn_mfma_f32_16x16x32_bf16(aF[0], bF, acc0, 0, 0, 0);
        acc1 = __builtin_amdgcn_mfma_f32_16x16x32_bf16(aF[1], bF, acc1, 0, 0, 0);
        float bo = bias[cidx];
        #pragma unroll
        for (int reg = 0; reg < 4; ++reg) {
            int row0 = m0 + q * 4 + reg;
            if (row0 < n)
                hout[(size_t)row0 * 128 + cidx] = f2bf(fmaxf(acc0[reg] + bo, 0.0f));
            int row1 = m0 + 16 + q * 4 + reg;
            if (row1 < n)
                hout[(size_t)row1 * 128 + cidx] = f2bf(fmaxf(acc1[reg] + bo, 0.0f));
        }
    }
}

// ---- high-occupancy coalesced mean aggregate: 16 lanes/node, 16B/lane,
// unroll-8 -> 8 independent 256B row reads in flight per node group
// (32 per wave); tail handled at 1/edge.
__global__ __launch_bounds__(256) void aggregate128_kernel(
    const bf16_t* __restrict__ h, const int* __restrict__ rowptr,
    const int* __restrict__ col, const float* __restrict__ inv,
    bf16_t* __restrict__ aggb, int N) {
    const int t = threadIdx.x;
    const int node = blockIdx.x * 16 + (t >> 4);
    const int li = t & 15;
    if (node >= N) return;
    const int lo = rowptr[node], hi = rowptr[node + 1];
    float acc[8];
    #pragma unroll
    for (int j = 0; j < 8; ++j) acc[j] = 0.0f;
    int e = lo;
    for (; e + 7 < hi; e += 8) {
        uint4 v0 = *(const uint4*)&h[(size_t)col[e + 0] * 128 + li * 8];
        uint4 v1 = *(const uint4*)&h[(size_t)col[e + 1] * 128 + li * 8];
        uint4 v2 = *(const uint4*)&h[(size_t)col[e + 2] * 128 + li * 8];
        uint4 v3 = *(const uint4*)&h[(size_t)col[e + 3] * 128 + li * 8];
        uint4 v4 = *(const uint4*)&h[(size_t)col[e + 4] * 128 + li * 8];
        uint4 v5 = *(const uint4*)&h[(size_t)col[e + 5] * 128 + li * 8];
        uint4 v6 = *(const uint4*)&h[(size_t)col[e + 6] * 128 + li * 8];
        uint4 v7 = *(const uint4*)&h[(size_t)col[e + 7] * 128 + li * 8];
        acc8(acc, v0); acc8(acc, v1); acc8(acc, v2); acc8(acc, v3);
        acc8(acc, v4); acc8(acc, v5); acc8(acc, v6); acc8(acc, v7);
    }
    if (e + 3 < hi) {
        uint4 v0 = *(const uint4*)&h[(size_t)col[e + 0] * 128 + li * 8];
        uint4 v1 = *(const uint4*)&h[(size_t)col[e + 1] * 128 + li * 8];
        uint4 v2 = *(const uint4*)&h[(size_t)col[e + 2] * 128 + li * 8];
        uint4 v3 = *(const uint4*)&h[(size_t)col[e + 3] * 128 + li * 8];
        acc8(acc, v0); acc8(acc, v1); acc8(acc, v2); acc8(acc, v3);
        e += 4;
    }
    for (; e < hi; ++e) {
        uint4 v0 = *(const uint4*)&h[(size_t)col[e] * 128 + li * 8];
        acc8(acc, v0);
    }
    const float iv = inv[node];
    uint4 pk;
    pk.x = (uint32)f2bf(acc[0] * iv) | ((uint32)f2bf(acc[1] * iv) << 16);
    pk.y = (uint32)f2bf(acc[2] * iv) | ((uint32)f2bf(acc[3] * iv) << 16);
    pk.z = (uint32)f2bf(acc[4] * iv) | ((uint32)f2bf(acc[5] * iv) << 16);
    pk.w = (uint32)f2bf(acc[6] * iv) | ((uint32)f2bf(acc[7] * iv) << 16);
    *(uint4*)&aggb[(size_t)node * 128 + li * 8] = pk;
}

// ---- layer 2: MFMA bf16 GEMM, K=256, fragments straight from global ------
__global__ __launch_bounds__(256) void layer128_mfma_kernel(
    const bf16_t* __restrict__ aggb, const bf16_t* __restrict__ hin,
    const bf16_t* __restrict__ wbf, const float* __restrict__ bias,
    bf16_t* __restrict__ hout, int n) {
    const int t = threadIdx.x;
    const int lane = t & 63;
    const int wave = t >> 6;
    const int r = lane & 15;
    const int q = lane >> 4;
    const int m0 = blockIdx.x * 64 + (wave >> 1) * 32;
    const int nb = (wave & 1) * 64;

    bf16x8 aF[2][8];
    #pragma unroll
    for (int mt = 0; mt < 2; ++mt) {
        int node = m0 + mt * 16 + r;
        if (node >= n) node = n - 1;
        const bf16_t* arow = aggb + (size_t)node * 128;
        const bf16_t* hrow = hin + (size_t)node * 128;
        #pragma unroll
        for (int ks = 0; ks < 4; ++ks)
            aF[mt][ks] = *(const bf16x8*)(arow + ks * 32 + q * 8);
        #pragma unroll
        for (int ks = 0; ks < 4; ++ks)
            aF[mt][4 + ks] = *(const bf16x8*)(hrow + ks * 32 + q * 8);
    }

    #pragma unroll
    for (int nt = 0; nt < 4; ++nt) {
        const int cidx = nb + nt * 16 + r;
        const bf16_t* wrow = wbf + (size_t)cidx * 256;
        f32x4 acc0 = {0.f, 0.f, 0.f, 0.f};
        f32x4 acc1 = {0.f, 0.f, 0.f, 0.f};
        #pragma unroll
        for (int ks = 0; ks < 8; ++ks) {
            bf16x8 bF = *(const bf16x8*)(wrow + ks * 32 + q * 8);
            acc0 = __builtin_amdgcn_mfma_f32_16x16x32_bf16(aF[0][ks], bF, acc0, 0, 0, 0);
            acc1 = __builtin_amdgcn_mfma_f32_16x16x32_bf16(aF[1][ks], bF, acc1, 0, 0, 0);
        }
        float bo = bias[cidx];
        #pragma unroll
        for (int reg = 0; reg < 4; ++reg) {
            int row0 = m0 + q * 4 + reg;
            if (row0 < n)
                hout[(size_t)row0 * 128 + cidx] = f2bf(fmaxf(acc0[reg] + bo, 0.0f));
            int row1 = m0 + 16 + q * 4 + reg;
            if (row1 < n)
                hout[(size_t)row1 * 128 + cidx] = f2bf(fmaxf(acc1[reg] + bo, 0.0f));
        }
    }
}

// ---- layer 3 + head fused via LDS tile -----------------------------------
__global__ __launch_bounds__(256) void layer128_head_mfma_kernel(
    const bf16_t* __restrict__ aggb, const bf16_t* __restrict__ hin,
    const bf16_t* __restrict__ wbf, const float* __restrict__ bias,
    const float* __restrict__ Wh, const float* __restrict__ bh,
    float* __restrict__ out, int n) {
    __shared__ bf16_t hs[64][132];

    const int t = threadIdx.x;
    const int lane = t & 63;
    const int wave = t >> 6;
    const int r = lane & 15;
    const int q = lane >> 4;
    const int n0 = blockIdx.x * 64;
    const int m0 = n0 + (wave >> 1) * 32;
    const int nb = (wave & 1) * 64;

    bf16x8 aF[2][8];
    #pragma unroll
    for (int mt = 0; mt < 2; ++mt) {
        int node = m0 + mt * 16 + r;
        if (node >= n) node = n - 1;
        const bf16_t* arow = aggb + (size_t)node * 128;
        const bf16_t* hrow = hin + (size_t)node * 128;
        #pragma unroll
        for (int ks = 0; ks < 4; ++ks)
            aF[mt][ks] = *(const bf16x8*)(arow + ks * 32 + q * 8);
        #pragma unroll
        for (int ks = 0; ks < 4; ++ks)
            aF[mt][4 + ks] = *(const bf16x8*)(hrow + ks * 32 + q * 8);
    }

    const int mloc = (wave >> 1) * 32;
    #pragma unroll
    for (int nt = 0; nt < 4; ++nt) {
        const int cidx = nb + nt * 16 + r;
        const bf16_t* wrow = wbf + (size_t)cidx * 256;
        f32x4 acc0 = {0.f, 0.f, 0.f, 0.f};
        f32x4 acc1 = {0.f, 0.f, 0.f, 0.f};
        #pragma unroll
        for (int ks = 0; ks < 8; ++ks) {
            bf16x8 bF = *(const bf16x8*)(wrow + ks * 32 + q * 8);
            acc0 = __builtin_amdgcn_mfma_f32_16x16x32_bf16(aF[0][ks], bF, acc0, 0, 0, 0);
            acc1 = __builtin_amdgcn_mfma_f32_16x16x32_bf16(aF[1][ks], bF, acc1, 0, 0, 0);
        }
        float bo = bias[cidx];
        #pragma unroll
        for (int reg = 0; reg < 4; ++reg) {
            hs[mloc + q * 4 + reg][cidx]      = f2bf(fmaxf(acc0[reg] + bo, 0.0f));
            hs[mloc + 16 + q * 4 + reg][cidx] = f2bf(fmaxf(acc1[reg] + bo, 0.0f));
        }
    }
    __syncthreads();

    const int nl = t >> 2;
    const int o  = t & 3;
    const int node = n0 + nl;
    if (node >= n) return;
    const float* wr = Wh + o * 128;
    float acc = bh[o];
    #pragma unroll
    for (int kb = 0; kb < 16; ++kb) {
        bf16x8 hv = *(const bf16x8*)&hs[nl][kb * 8];
        float4 w0 = *(const float4*)&wr[kb * 8];
        float4 w1 = *(const float4*)&wr[kb * 8 + 4];
        acc = fmaf(bf2f((bf16_t)hv[0]), w0.x, acc);
        acc = fmaf(bf2f((bf16_t)hv[1]), w0.y, acc);
        acc = fmaf(bf2f((bf16_t)hv[2]), w0.z, acc);
        acc = fmaf(bf2f((bf16_t)hv[3]), w0.w, acc);
        acc = fmaf(bf2f((bf16_t)hv[4]), w1.x, acc);
        acc = fmaf(bf2f((bf16_t)hv[5]), w1.y, acc);
        acc = fmaf(bf2f((bf16_t)hv[6]), w1.z, acc);
        acc = fmaf(bf2f((bf16_t)hv[7]), w1.w, acc);
    }
    out[(size_t)node * 4 + o] = acc;
}

extern "C" void kernel_launch(void* const* d_in, const int* in_sizes, int n_in,
                              void* d_out, int out_size, void* d_ws, size_t ws_size,
                              hipStream_t stream) {
    const float* x   = (const float*)d_in[0];
    const int*   ei  = (const int*)d_in[1];
    const float* Wl1 = (const float*)d_in[2];
    const float* Wr1 = (const float*)d_in[3];
    const float* b1  = (const float*)d_in[4];
    const float* Wl2 = (const float*)d_in[5];
    const float* Wr2 = (const float*)d_in[6];
    const float* b2  = (const float*)d_in[7];
    const float* Wl3 = (const float*)d_in[8];
    const float* Wr3 = (const float*)d_in[9];
    const float* b3  = (const float*)d_in[10];
    const float* Wh  = (const float*)d_in[11];
    const float* bh  = (const float*)d_in[12];
    float* out = (float*)d_out;

    const int N = in_sizes[0] / 16;
    const int E = in_sizes[1] / 2;
    const int* src = ei;
    const int* dst = ei + E;

    const int nScanBlocks = (N + SCAN_CHUNK - 1) / SCAN_CHUNK;
    const int nZero = (N + 255) >> 8;

    int* deg       = (int*)d_ws;                       // N
    int* rowptr    = deg + N;                          // N+1 (pad 8)
    int* cursor    = rowptr + (N + 8);                 // N
    int* blocksum  = cursor + N;                       // pad 64
    int* col       = blocksum + 64;                    // E
    float* inv     = (float*)(col + E);                // N
    bf16_t* aggb   = (bf16_t*)(inv + N);               // N*128 bf16
    bf16_t* hA     = aggb + (size_t)N * 128;           // N*128 bf16
    bf16_t* hB     = hA + (size_t)N * 128;             // N*128 bf16
    bf16_t* wbf1   = hB + (size_t)N * 128;             // 128*32 bf16
    bf16_t* wbf2   = wbf1 + 128 * 32;                  // 128*256 bf16
    bf16_t* wbf3   = wbf2 + 128 * 256;                 // 128*256 bf16

    const int B = 256;
    auto blocks = [](long total, int b) { return (int)((total + b - 1) / b); };

    // ---- setup + CSR build (5 dispatches) ----
    prep_kernel<<<nZero + 272, B, 0, stream>>>(deg, N, Wl1, Wr1, wbf1,
                                               Wl2, Wr2, wbf2, Wl3, Wr3, wbf3);
    count_deg_kernel<<<blocks(E, B), B, 0, stream>>>(dst, deg, E);
    scan_partial_kernel<<<nScanBlocks, B, 0, stream>>>(deg, blocksum, N);
    scan_final_kernel<<<nScanBlocks, B, 0, stream>>>(deg, blocksum, rowptr, cursor, inv, N);
    fill_csr_kernel<<<blocks(E, B), B, 0, stream>>>(src, dst, cursor, col, E);

    // ---- layer 1: fused x-gather + MFMA (K=32) ----
    layer16_fused_kernel<<<blocks(N, 64), B, 0, stream>>>(
        x, rowptr, col, inv, wbf1, b1, hA, N);

    // ---- layer 2: aggregate + MFMA GEMM ----
    aggregate128_kernel<<<blocks(N, 16), B, 0, stream>>>(hA, rowptr, col, inv, aggb, N);
    layer128_mfma_kernel<<<blocks(N, 64), B, 0, stream>>>(aggb, hA, wbf2, b2, hB, N);

    // ---- layer 3 + head fused ----
    aggregate128_kernel<<<blocks(N, 16), B, 0, stream>>>(hB, rowptr, col, inv, aggb, N);
    layer128_head_mfma_kernel<<<blocks(N, 64), B, 0, stream>>>(
        aggb, hB, wbf3, b3, Wh, bh, out, N);
}

// Round 13
// 296.759 us; speedup vs baseline: 1.5271x; 1.0137x over previous
//
#include <hip/hip_runtime.h>
#include <hip/hip_bf16.h>

// ---------------------------------------------------------------------------
// GraphSAGE (3x SAGEConv mean + linear head), CSR gather formulation.
// R13 = R10 (best: 295us) + layer16 full-wave gather:
//   x-gather split by edge parity across quad-pairs (q0/q1 even edges,
//   q2/q3 odd edges), partials combined with __shfl_xor(32) — halves the
//   serial gather chain and puts all 64 lanes to work (was: half idle).
// aggregate128 reverted to R10's exact unroll-4 (R12's unroll-8 measured
// neutral -> gathers are L3-service-bound, not MLP-bound).
// Established: prep merge, split aggregate/GEMM, no-LDS MFMA GEMMs (K=256),
// head fused into layer-3 epilogue. R11 lesson: no 32-counter atomic sorts.
// ---------------------------------------------------------------------------

#define SCAN_CHUNK 2048

typedef unsigned short bf16_t;
typedef unsigned int uint32;
typedef __attribute__((ext_vector_type(8))) short bf16x8;   // 8 bf16 = 4 VGPRs
typedef __attribute__((ext_vector_type(4))) float f32x4;

__device__ __forceinline__ bf16_t f2bf(float f) {
    uint32 u = __float_as_uint(f);
    u += 0x7fff + ((u >> 16) & 1);           // round-to-nearest-even
    return (bf16_t)(u >> 16);
}
__device__ __forceinline__ float bf2f(bf16_t b) {
    return __uint_as_float((uint32)b << 16);
}
__device__ __forceinline__ void acc8(float* acc, uint4 v) {
    acc[0] += bf2f((bf16_t)(v.x & 0xffff)); acc[1] += bf2f((bf16_t)(v.x >> 16));
    acc[2] += bf2f((bf16_t)(v.y & 0xffff)); acc[3] += bf2f((bf16_t)(v.y >> 16));
    acc[4] += bf2f((bf16_t)(v.z & 0xffff)); acc[5] += bf2f((bf16_t)(v.z >> 16));
    acc[6] += bf2f((bf16_t)(v.w & 0xffff)); acc[7] += bf2f((bf16_t)(v.w >> 16));
}

// ---- setup: zero deg + convert all three weight matrices to bf16 ----------
__global__ __launch_bounds__(256) void prep_kernel(
    int* __restrict__ deg, int N,
    const float* __restrict__ Wl1, const float* __restrict__ Wr1, bf16_t* __restrict__ w1,
    const float* __restrict__ Wl2, const float* __restrict__ Wr2, bf16_t* __restrict__ w2,
    const float* __restrict__ Wl3, const float* __restrict__ Wr3, bf16_t* __restrict__ w3) {
    const int nZero = (N + 255) >> 8;
    const int b = blockIdx.x;
    const int t = threadIdx.x;
    if (b < nZero) {
        int i = b * 256 + t;
        if (i < N) deg[i] = 0;
    } else if (b < nZero + 16) {
        int idx = (b - nZero) * 256 + t;         // 0..4095
        int o = idx >> 5, k = idx & 31;
        float v = (k < 16) ? Wl1[o * 16 + k] : Wr1[o * 16 + k - 16];
        w1[idx] = f2bf(v);
    } else if (b < nZero + 144) {
        int idx = (b - nZero - 16) * 256 + t;    // 0..32767
        int o = idx >> 8, k = idx & 255;
        float v = (k < 128) ? Wl2[o * 128 + k] : Wr2[o * 128 + k - 128];
        w2[idx] = f2bf(v);
    } else {
        int idx = (b - nZero - 144) * 256 + t;
        int o = idx >> 8, k = idx & 255;
        float v = (k < 128) ? Wl3[o * 128 + k] : Wr3[o * 128 + k - 128];
        w3[idx] = f2bf(v);
    }
}

__global__ void count_deg_kernel(const int* __restrict__ dst, int* __restrict__ deg, int E) {
    int e = blockIdx.x * 256 + threadIdx.x;
    if (e < E) atomicAdd(&deg[dst[e]], 1);
}

__global__ __launch_bounds__(256) void scan_partial_kernel(
    const int* __restrict__ deg, int* __restrict__ blocksum, int N) {
    __shared__ int s[256];
    const int t = threadIdx.x;
    const int base = blockIdx.x * SCAN_CHUNK + t * 8;
    int sum = 0;
    #pragma unroll
    for (int j = 0; j < 8; ++j) {
        int i = base + j;
        if (i < N) sum += deg[i];
    }
    s[t] = sum;
    __syncthreads();
    #pragma unroll
    for (int off = 128; off > 0; off >>= 1) {
        if (t < off) s[t] += s[t + off];
        __syncthreads();
    }
    if (t == 0) blocksum[blockIdx.x] = s[0];
}

__global__ __launch_bounds__(256) void scan_final_kernel(
    const int* __restrict__ deg, const int* __restrict__ blocksum,
    int* __restrict__ rowptr, int* __restrict__ cursor,
    float* __restrict__ inv, int N) {
    __shared__ int s[256];
    __shared__ int blockoff_s;
    const int t = threadIdx.x;
    if (t == 0) {
        int off = 0;
        for (int b = 0; b < (int)blockIdx.x; ++b) off += blocksum[b];
        blockoff_s = off;
    }
    const int base = blockIdx.x * SCAN_CHUNK + t * 8;
    int v[8];
    int sum = 0;
    #pragma unroll
    for (int j = 0; j < 8; ++j) {
        int i = base + j;
        v[j] = (i < N) ? deg[i] : 0;
        sum += v[j];
    }
    s[t] = sum;
    __syncthreads();
    for (int off = 1; off < 256; off <<= 1) {
        int val = (t >= off) ? s[t - off] : 0;
        __syncthreads();
        s[t] += val;
        __syncthreads();
    }
    int run = blockoff_s + ((t == 0) ? 0 : s[t - 1]);
    #pragma unroll
    for (int j = 0; j < 8; ++j) {
        int i = base + j;
        if (i < N) {
            rowptr[i] = run;
            cursor[i] = run;
            inv[i] = 1.0f / (float)max(v[j], 1);
            run += v[j];
        }
    }
    if ((int)blockIdx.x == (int)gridDim.x - 1 && t == 255) rowptr[N] = run;
}

__global__ void fill_csr_kernel(const int* __restrict__ src, const int* __restrict__ dst,
                                int* __restrict__ cursor, int* __restrict__ col, int E) {
    int e = blockIdx.x * 256 + threadIdx.x;
    if (e >= E) return;
    int pos = atomicAdd(&cursor[dst[e]], 1);
    col[pos] = src[e];
}

// ---- layer 1 fused: full-wave x-gather + MFMA (K=32) ---------------------
// Quad-pairs split edges by parity: q0/q1 even edges, q2/q3 odd edges;
// feature half fo = (q&1)*8. Partials combined via shfl_xor(32); then
// q0/q1 hold the mean frag, q2/q3 load self-x frag.
__global__ __launch_bounds__(256) void layer16_fused_kernel(
    const float* __restrict__ x, const int* __restrict__ rowptr,
    const int* __restrict__ col, const float* __restrict__ inv,
    const bf16_t* __restrict__ wbf1, const float* __restrict__ bias,
    bf16_t* __restrict__ hout, int n) {
    const int t = threadIdx.x;
    const int lane = t & 63;
    const int wave = t >> 6;
    const int r = lane & 15;
    const int q = lane >> 4;
    const int m0 = blockIdx.x * 64 + (wave >> 1) * 32;
    const int nb = (wave & 1) * 64;
    const int qh = q >> 1;            // 0: even edges, 1: odd edges
    const int fo = (q & 1) * 8;       // feature half

    bf16x8 aF[2];
    #pragma unroll
    for (int mt = 0; mt < 2; ++mt) {
        int node = m0 + mt * 16 + r;
        if (node >= n) node = n - 1;
        const int lo = rowptr[node], hi = rowptr[node + 1];
        float acc[8];
        #pragma unroll
        for (int j = 0; j < 8; ++j) acc[j] = 0.f;
        // all 4 quads gather: this quad's parity slice of the edge list
        int e = lo + qh;
        for (; e + 2 < hi; e += 4) {            // 2 edges/iter -> 4 loads in flight
            int s0 = col[e], s1 = col[e + 2];
            float4 u0 = *(const float4*)&x[s0 * 16 + fo];
            float4 u1 = *(const float4*)&x[s0 * 16 + fo + 4];
            float4 u2 = *(const float4*)&x[s1 * 16 + fo];
            float4 u3 = *(const float4*)&x[s1 * 16 + fo + 4];
            acc[0] += u0.x + u2.x; acc[1] += u0.y + u2.y;
            acc[2] += u0.z + u2.z; acc[3] += u0.w + u2.w;
            acc[4] += u1.x + u3.x; acc[5] += u1.y + u3.y;
            acc[6] += u1.z + u3.z; acc[7] += u1.w + u3.w;
        }
        if (e < hi) {
            int s0 = col[e];
            float4 u0 = *(const float4*)&x[s0 * 16 + fo];
            float4 u1 = *(const float4*)&x[s0 * 16 + fo + 4];
            acc[0] += u0.x; acc[1] += u0.y; acc[2] += u0.z; acc[3] += u0.w;
            acc[4] += u1.x; acc[5] += u1.y; acc[6] += u1.z; acc[7] += u1.w;
        }
        // combine even/odd partials across quad-pairs (lane ^ 32)
        #pragma unroll
        for (int j = 0; j < 8; ++j)
            acc[j] += __shfl_xor(acc[j], 32, 64);

        if (q < 2) {
            float iv = inv[node];
            #pragma unroll
            for (int j = 0; j < 8; ++j) aF[mt][j] = (short)f2bf(acc[j] * iv);
        } else {
            float4 u0 = *(const float4*)&x[node * 16 + (q - 2) * 8];
            float4 u1 = *(const float4*)&x[node * 16 + (q - 2) * 8 + 4];
            aF[mt][0] = (short)f2bf(u0.x); aF[mt][1] = (short)f2bf(u0.y);
            aF[mt][2] = (short)f2bf(u0.z); aF[mt][3] = (short)f2bf(u0.w);
            aF[mt][4] = (short)f2bf(u1.x); aF[mt][5] = (short)f2bf(u1.y);
            aF[mt][6] = (short)f2bf(u1.z); aF[mt][7] = (short)f2bf(u1.w);
        }
    }

    #pragma unroll
    for (int nt = 0; nt < 4; ++nt) {
        const int cidx = nb + nt * 16 + r;
        bf16x8 bF = *(const bf16x8*)(wbf1 + (size_t)cidx * 32 + q * 8);
        f32x4 acc0 = {0.f, 0.f, 0.f, 0.f};
        f32x4 acc1 = {0.f, 0.f, 0.f, 0.f};
        acc0 = __builtin_amdgcn_mfma_f32_16x16x32_bf16(aF[0], bF, acc0, 0, 0, 0);
        acc1 = __builtin_amdgcn_mfma_f32_16x16x32_bf16(aF[1], bF, acc1, 0, 0, 0);
        float bo = bias[cidx];
        #pragma unroll
        for (int reg = 0; reg < 4; ++reg) {
            int row0 = m0 + q * 4 + reg;
            if (row0 < n)
                hout[(size_t)row0 * 128 + cidx] = f2bf(fmaxf(acc0[reg] + bo, 0.0f));
            int row1 = m0 + 16 + q * 4 + reg;
            if (row1 < n)
                hout[(size_t)row1 * 128 + cidx] = f2bf(fmaxf(acc1[reg] + bo, 0.0f));
        }
    }
}

// ---- high-occupancy coalesced mean aggregate (R10 exact): 16 lanes/node,
// 16B/lane, unroll-4 -> 16 independent 256B row reads in flight per wave.
__global__ __launch_bounds__(256) void aggregate128_kernel(
    const bf16_t* __restrict__ h, const int* __restrict__ rowptr,
    const int* __restrict__ col, const float* __restrict__ inv,
    bf16_t* __restrict__ aggb, int N) {
    const int t = threadIdx.x;
    const int node = blockIdx.x * 16 + (t >> 4);
    const int li = t & 15;
    if (node >= N) return;
    const int lo = rowptr[node], hi = rowptr[node + 1];
    float acc[8];
    #pragma unroll
    for (int j = 0; j < 8; ++j) acc[j] = 0.0f;
    int e = lo;
    for (; e + 3 < hi; e += 4) {
        int s0 = col[e], s1 = col[e + 1], s2 = col[e + 2], s3 = col[e + 3];
        uint4 v0 = *(const uint4*)&h[(size_t)s0 * 128 + li * 8];
        uint4 v1 = *(const uint4*)&h[(size_t)s1 * 128 + li * 8];
        uint4 v2 = *(const uint4*)&h[(size_t)s2 * 128 + li * 8];
        uint4 v3 = *(const uint4*)&h[(size_t)s3 * 128 + li * 8];
        acc8(acc, v0);
        acc8(acc, v1);
        acc8(acc, v2);
        acc8(acc, v3);
    }
    for (; e < hi; ++e) {
        uint4 v0 = *(const uint4*)&h[(size_t)col[e] * 128 + li * 8];
        acc8(acc, v0);
    }
    const float iv = inv[node];
    uint4 pk;
    pk.x = (uint32)f2bf(acc[0] * iv) | ((uint32)f2bf(acc[1] * iv) << 16);
    pk.y = (uint32)f2bf(acc[2] * iv) | ((uint32)f2bf(acc[3] * iv) << 16);
    pk.z = (uint32)f2bf(acc[4] * iv) | ((uint32)f2bf(acc[5] * iv) << 16);
    pk.w = (uint32)f2bf(acc[6] * iv) | ((uint32)f2bf(acc[7] * iv) << 16);
    *(uint4*)&aggb[(size_t)node * 128 + li * 8] = pk;
}

// ---- layer 2: MFMA bf16 GEMM, K=256, fragments straight from global ------
__global__ __launch_bounds__(256) void layer128_mfma_kernel(
    const bf16_t* __restrict__ aggb, const bf16_t* __restrict__ hin,
    const bf16_t* __restrict__ wbf, const float* __restrict__ bias,
    bf16_t* __restrict__ hout, int n) {
    const int t = threadIdx.x;
    const int lane = t & 63;
    const int wave = t >> 6;
    const int r = lane & 15;
    const int q = lane >> 4;
    const int m0 = blockIdx.x * 64 + (wave >> 1) * 32;
    const int nb = (wave & 1) * 64;

    bf16x8 aF[2][8];
    #pragma unroll
    for (int mt = 0; mt < 2; ++mt) {
        int node = m0 + mt * 16 + r;
        if (node >= n) node = n - 1;
        const bf16_t* arow = aggb + (size_t)node * 128;
        const bf16_t* hrow = hin + (size_t)node * 128;
        #pragma unroll
        for (int ks = 0; ks < 4; ++ks)
            aF[mt][ks] = *(const bf16x8*)(arow + ks * 32 + q * 8);
        #pragma unroll
        for (int ks = 0; ks < 4; ++ks)
            aF[mt][4 + ks] = *(const bf16x8*)(hrow + ks * 32 + q * 8);
    }

    #pragma unroll
    for (int nt = 0; nt < 4; ++nt) {
        const int cidx = nb + nt * 16 + r;
        const bf16_t* wrow = wbf + (size_t)cidx * 256;
        f32x4 acc0 = {0.f, 0.f, 0.f, 0.f};
        f32x4 acc1 = {0.f, 0.f, 0.f, 0.f};
        #pragma unroll
        for (int ks = 0; ks < 8; ++ks) {
            bf16x8 bF = *(const bf16x8*)(wrow + ks * 32 + q * 8);
            acc0 = __builtin_amdgcn_mfma_f32_16x16x32_bf16(aF[0][ks], bF, acc0, 0, 0, 0);
            acc1 = __builtin_amdgcn_mfma_f32_16x16x32_bf16(aF[1][ks], bF, acc1, 0, 0, 0);
        }
        float bo = bias[cidx];
        #pragma unroll
        for (int reg = 0; reg < 4; ++reg) {
            int row0 = m0 + q * 4 + reg;
            if (row0 < n)
                hout[(size_t)row0 * 128 + cidx] = f2bf(fmaxf(acc0[reg] + bo, 0.0f));
            int row1 = m0 + 16 + q * 4 + reg;
            if (row1 < n)
                hout[(size_t)row1 * 128 + cidx] = f2bf(fmaxf(acc1[reg] + bo, 0.0f));
        }
    }
}

// ---- layer 3 + head fused via LDS tile -----------------------------------
__global__ __launch_bounds__(256) void layer128_head_mfma_kernel(
    const bf16_t* __restrict__ aggb, const bf16_t* __restrict__ hin,
    const bf16_t* __restrict__ wbf, const float* __restrict__ bias,
    const float* __restrict__ Wh, const float* __restrict__ bh,
    float* __restrict__ out, int n) {
    __shared__ bf16_t hs[64][132];

    const int t = threadIdx.x;
    const int lane = t & 63;
    const int wave = t >> 6;
    const int r = lane & 15;
    const int q = lane >> 4;
    const int n0 = blockIdx.x * 64;
    const int m0 = n0 + (wave >> 1) * 32;
    const int nb = (wave & 1) * 64;

    bf16x8 aF[2][8];
    #pragma unroll
    for (int mt = 0; mt < 2; ++mt) {
        int node = m0 + mt * 16 + r;
        if (node >= n) node = n - 1;
        const bf16_t* arow = aggb + (size_t)node * 128;
        const bf16_t* hrow = hin + (size_t)node * 128;
        #pragma unroll
        for (int ks = 0; ks < 4; ++ks)
            aF[mt][ks] = *(const bf16x8*)(arow + ks * 32 + q * 8);
        #pragma unroll
        for (int ks = 0; ks < 4; ++ks)
            aF[mt][4 + ks] = *(const bf16x8*)(hrow + ks * 32 + q * 8);
    }

    const int mloc = (wave >> 1) * 32;
    #pragma unroll
    for (int nt = 0; nt < 4; ++nt) {
        const int cidx = nb + nt * 16 + r;
        const bf16_t* wrow = wbf + (size_t)cidx * 256;
        f32x4 acc0 = {0.f, 0.f, 0.f, 0.f};
        f32x4 acc1 = {0.f, 0.f, 0.f, 0.f};
        #pragma unroll
        for (int ks = 0; ks < 8; ++ks) {
            bf16x8 bF = *(const bf16x8*)(wrow + ks * 32 + q * 8);
            acc0 = __builtin_amdgcn_mfma_f32_16x16x32_bf16(aF[0][ks], bF, acc0, 0, 0, 0);
            acc1 = __builtin_amdgcn_mfma_f32_16x16x32_bf16(aF[1][ks], bF, acc1, 0, 0, 0);
        }
        float bo = bias[cidx];
        #pragma unroll
        for (int reg = 0; reg < 4; ++reg) {
            hs[mloc + q * 4 + reg][cidx]      = f2bf(fmaxf(acc0[reg] + bo, 0.0f));
            hs[mloc + 16 + q * 4 + reg][cidx] = f2bf(fmaxf(acc1[reg] + bo, 0.0f));
        }
    }
    __syncthreads();

    const int nl = t >> 2;
    const int o  = t & 3;
    const int node = n0 + nl;
    if (node >= n) return;
    const float* wr = Wh + o * 128;
    float acc = bh[o];
    #pragma unroll
    for (int kb = 0; kb < 16; ++kb) {
        bf16x8 hv = *(const bf16x8*)&hs[nl][kb * 8];
        float4 w0 = *(const float4*)&wr[kb * 8];
        float4 w1 = *(const float4*)&wr[kb * 8 + 4];
        acc = fmaf(bf2f((bf16_t)hv[0]), w0.x, acc);
        acc = fmaf(bf2f((bf16_t)hv[1]), w0.y, acc);
        acc = fmaf(bf2f((bf16_t)hv[2]), w0.z, acc);
        acc = fmaf(bf2f((bf16_t)hv[3]), w0.w, acc);
        acc = fmaf(bf2f((bf16_t)hv[4]), w1.x, acc);
        acc = fmaf(bf2f((bf16_t)hv[5]), w1.y, acc);
        acc = fmaf(bf2f((bf16_t)hv[6]), w1.z, acc);
        acc = fmaf(bf2f((bf16_t)hv[7]), w1.w, acc);
    }
    out[(size_t)node * 4 + o] = acc;
}

extern "C" void kernel_launch(void* const* d_in, const int* in_sizes, int n_in,
                              void* d_out, int out_size, void* d_ws, size_t ws_size,
                              hipStream_t stream) {
    const float* x   = (const float*)d_in[0];
    const int*   ei  = (const int*)d_in[1];
    const float* Wl1 = (const float*)d_in[2];
    const float* Wr1 = (const float*)d_in[3];
    const float* b1  = (const float*)d_in[4];
    const float* Wl2 = (const float*)d_in[5];
    const float* Wr2 = (const float*)d_in[6];
    const float* b2  = (const float*)d_in[7];
    const float* Wl3 = (const float*)d_in[8];
    const float* Wr3 = (const float*)d_in[9];
    const float* b3  = (const float*)d_in[10];
    const float* Wh  = (const float*)d_in[11];
    const float* bh  = (const float*)d_in[12];
    float* out = (float*)d_out;

    const int N = in_sizes[0] / 16;
    const int E = in_sizes[1] / 2;
    const int* src = ei;
    const int* dst = ei + E;

    const int nScanBlocks = (N + SCAN_CHUNK - 1) / SCAN_CHUNK;
    const int nZero = (N + 255) >> 8;

    int* deg       = (int*)d_ws;                       // N
    int* rowptr    = deg + N;                          // N+1 (pad 8)
    int* cursor    = rowptr + (N + 8);                 // N
    int* blocksum  = cursor + N;                       // pad 64
    int* col       = blocksum + 64;                    // E
    float* inv     = (float*)(col + E);                // N
    bf16_t* aggb   = (bf16_t*)(inv + N);               // N*128 bf16
    bf16_t* hA     = aggb + (size_t)N * 128;           // N*128 bf16
    bf16_t* hB     = hA + (size_t)N * 128;             // N*128 bf16
    bf16_t* wbf1   = hB + (size_t)N * 128;             // 128*32 bf16
    bf16_t* wbf2   = wbf1 + 128 * 32;                  // 128*256 bf16
    bf16_t* wbf3   = wbf2 + 128 * 256;                 // 128*256 bf16

    const int B = 256;
    auto blocks = [](long total, int b) { return (int)((total + b - 1) / b); };

    // ---- setup + CSR build (5 dispatches) ----
    prep_kernel<<<nZero + 272, B, 0, stream>>>(deg, N, Wl1, Wr1, wbf1,
                                               Wl2, Wr2, wbf2, Wl3, Wr3, wbf3);
    count_deg_kernel<<<blocks(E, B), B, 0, stream>>>(dst, deg, E);
    scan_partial_kernel<<<nScanBlocks, B, 0, stream>>>(deg, blocksum, N);
    scan_final_kernel<<<nScanBlocks, B, 0, stream>>>(deg, blocksum, rowptr, cursor, inv, N);
    fill_csr_kernel<<<blocks(E, B), B, 0, stream>>>(src, dst, cursor, col, E);

    // ---- layer 1: full-wave fused x-gather + MFMA (K=32) ----
    layer16_fused_kernel<<<blocks(N, 64), B, 0, stream>>>(
        x, rowptr, col, inv, wbf1, b1, hA, N);

    // ---- layer 2: aggregate + MFMA GEMM ----
    aggregate128_kernel<<<blocks(N, 16), B, 0, stream>>>(hA, rowptr, col, inv, aggb, N);
    layer128_mfma_kernel<<<blocks(N, 64), B, 0, stream>>>(aggb, hA, wbf2, b2, hB, N);

    // ---- layer 3 + head fused ----
    aggregate128_kernel<<<blocks(N, 16), B, 0, stream>>>(hB, rowptr, col, inv, aggb, N);
    layer128_head_mfma_kernel<<<blocks(N, 64), B, 0, stream>>>(
        aggb, hB, wbf3, b3, Wh, bh, out, N);
}